// Round 23
// baseline (139.926 us; speedup 1.0000x reference)
//
#include <hip/hip_runtime.h>

#define DM   1024
#define NH   16
#define DK   64
#define SEQ  2048
#define BATCH 2

typedef __attribute__((ext_vector_type(8))) short bf16x8;
typedef __attribute__((ext_vector_type(4))) float f32x4;
typedef __attribute__((ext_vector_type(16))) float f32x16;

__device__ __forceinline__ unsigned short f2bf(float f) {
    unsigned int u = __builtin_bit_cast(unsigned int, f);
    u += 0x7FFFu + ((u >> 16) & 1u);
    return (unsigned short)(u >> 16);
}
__device__ __forceinline__ float bf2f(unsigned short u) {
    return __builtin_bit_cast(float, ((unsigned int)u) << 16);
}

// ---------------------------------------------------------------------------
// fp32 -> bf16 pre-convert: x (4M elems), Wq/Wk/Wv (-> wqkvb contig), Wo.
// ---------------------------------------------------------------------------
__global__ __launch_bounds__(256)
void cvt_kernel(const float* __restrict__ x,
                const float* __restrict__ wq, const float* __restrict__ wk,
                const float* __restrict__ wv, const float* __restrict__ wo,
                unsigned short* __restrict__ xb,
                unsigned short* __restrict__ wqkvb,
                unsigned short* __restrict__ wob)
{
    const int seg = blockIdx.y;
    const float* src;
    unsigned short* dst;
    int n;
    if (seg == 0)      { src = x;  dst = xb;                  n = 4 << 20; }
    else if (seg == 1) { src = wq; dst = wqkvb;               n = 1 << 20; }
    else if (seg == 2) { src = wk; dst = wqkvb + (1 << 20);   n = 1 << 20; }
    else if (seg == 3) { src = wv; dst = wqkvb + (2 << 20);   n = 1 << 20; }
    else               { src = wo; dst = wob;                 n = 1 << 20; }
    for (int i = (blockIdx.x * 256 + threadIdx.x) * 4; i < n; i += 1024 * 256 * 4) {
        const float4 v = *reinterpret_cast<const float4*>(&src[i]);
        ushort4 o;
        o.x = f2bf(v.x); o.y = f2bf(v.y); o.z = f2bf(v.z); o.w = f2bf(v.w);
        *reinterpret_cast<ushort4*>(&dst[i]) = o;
    }
}

// ---------------------------------------------------------------------------
// bf16 GEMM, m97 structure, BK=32 single-buffered, DEFAULT block order.
// r22: BM template — BM=64 doubles resident blocks (QKV 3->6/CU,
// O-proj 2->4/CU); this GEMM shape is latency/TLP-bound (r20: VALUBusy
// 13%, occ 19%), the r14 lever. acc halves to 32 VGPR.
// C[m][n] = sum_k A[m][k] * W[n][k] + bias[n]
// MODE 0: z in {0,1,2} -> Q (scaled log2e/8) / K / V^T   (bf16 out)
// MODE 1: + residual (fp32 math) -> h stored BF16
// ---------------------------------------------------------------------------
template <int MODE, int BM, int BN>
__global__ __launch_bounds__(256)
void gemm2_kernel(const unsigned short* __restrict__ Ab,
                  const unsigned short* __restrict__ Wall,
                  const float* __restrict__ B0, const float* __restrict__ B1,
                  const float* __restrict__ B2,
                  unsigned short* __restrict__ q_ws,
                  unsigned short* __restrict__ k_ws,
                  unsigned short* __restrict__ vt_ws,
                  const float* __restrict__ resid,
                  unsigned short* __restrict__ hb_ws)
{
    __shared__ unsigned short sA[BM * 32];
    __shared__ unsigned short sB[BN * 32];

    const int tid = threadIdx.x, lane = tid & 63, wid = tid >> 6;
    const int n0 = blockIdx.x * BN, m0 = blockIdx.y * BM;
    const int z  = (MODE == 0) ? blockIdx.z : 0;
    const unsigned short* W = Wall + (size_t)z * (1 << 20);
    const float* bias = (MODE == 0) ? (z == 0 ? B0 : (z == 1 ? B1 : B2)) : B0;

    const int g = lane >> 4, lq = lane & 15;
    const int wr = wid >> 1, wc = wid & 1;
    const int rA = lane >> 2;            // row within 16-row chunk
    const int csh = (lane & 3) * 8;      // col (shorts) within 32-col tile

    f32x4 acc[BM / 32][BN / 32] = {};

    for (int k0 = 0; k0 < DM; k0 += 32) {
        #pragma unroll
        for (int i = 0; i < BM / 64; ++i) {
            const int c = wid * (BM / 64) + i;   // 1KB chunk = 16 rows
            __builtin_amdgcn_global_load_lds(
                (const __attribute__((address_space(1))) unsigned int*)
                    &Ab[(size_t)(m0 + c * 16 + rA) * DM + k0 + csh],
                (__attribute__((address_space(3))) unsigned int*)&sA[c * 512],
                16, 0, 0);
        }
        #pragma unroll
        for (int i = 0; i < BN / 64; ++i) {
            const int c = wid * (BN / 64) + i;
            __builtin_amdgcn_global_load_lds(
                (const __attribute__((address_space(1))) unsigned int*)
                    &W[(size_t)(n0 + c * 16 + rA) * DM + k0 + csh],
                (__attribute__((address_space(3))) unsigned int*)&sB[c * 512],
                16, 0, 0);
        }
        __syncthreads();   // implicit vmcnt(0) drains the DMA

        bf16x8 a[BM / 32], b[BN / 32];
        #pragma unroll
        for (int m = 0; m < BM / 32; ++m)
            a[m] = *reinterpret_cast<const bf16x8*>(&sA[(wr * (BM / 2) + m * 16 + lq) * 32 + 8 * g]);
        #pragma unroll
        for (int n = 0; n < BN / 32; ++n)
            b[n] = *reinterpret_cast<const bf16x8*>(&sB[(wc * (BN / 2) + n * 16 + lq) * 32 + 8 * g]);
        #pragma unroll
        for (int m = 0; m < BM / 32; ++m)
            #pragma unroll
            for (int n = 0; n < BN / 32; ++n)
                acc[m][n] = __builtin_amdgcn_mfma_f32_16x16x32_bf16(
                    a[m], b[n], acc[m][n], 0, 0, 0);
        __syncthreads();
    }

    // epilogue: D row = 4*g + j (A-side), col = lq (B-side)
    #pragma unroll
    for (int m = 0; m < BM / 32; ++m) {
        #pragma unroll
        for (int n = 0; n < BN / 32; ++n) {
            #pragma unroll
            for (int j = 0; j < 4; ++j) {
                const int row = m0 + wr * (BM / 2) + m * 16 + 4 * g + j;
                const int col = n0 + wc * (BN / 2) + n * 16 + lq;
                float v = acc[m][n][j] + bias[col];
                if constexpr (MODE == 0) {
                    const int b_ = row >> 11, s = row & (SEQ - 1);
                    const int hh = col >> 6,  d = col & (DK - 1);
                    if (z == 0)   // fold 1/sqrt(64) * log2(e): attn in exp2 domain
                        q_ws[(((size_t)(b_ * NH + hh) * SEQ + s) << 6) + d] = f2bf(v * 0.18033688f);
                    else if (z == 1)
                        k_ws[(((size_t)(b_ * NH + hh) * SEQ + s) << 6) + d] = f2bf(v);
                    else
                        vt_ws[((size_t)(b_ * NH + hh) * DK + d) * SEQ + s] = f2bf(v);
                } else {
                    const size_t idx = (size_t)row * DM + col;
                    hb_ws[idx] = f2bf(v + resid[idx]);   // residual fp32, store bf16
                }
            }
        }
    }
}

// ---------------------------------------------------------------------------
// Flash attention, 32x32x16 swapped-operand, fixed-max softmax, in-block
// 2-way split-K + XCD remap — EXACT r18 measured-best (48.3us, FETCH 12MB).
// ---------------------------------------------------------------------------
__global__ __launch_bounds__(512)
void attn_kernel(const unsigned short* __restrict__ q_ws,
                 const unsigned short* __restrict__ k_ws,
                 const unsigned short* __restrict__ vt_ws,
                 unsigned short* __restrict__ ao_ws)
{
    // stream s: K bufs lds4[2s],[2s+1]; V bufs lds4[4+2s],[4+2s+1]
    __shared__ unsigned short lds4[8][4096];

    const int tid = threadIdx.x;
    const int lane = tid & 63, wid = tid >> 6;       // wid 0..7
    const int s = wid >> 2, w4 = wid & 3;
    const int l31 = lane & 31, h = lane >> 5;

    // XCD-aware remap (bijection over 512 blocks)
    const int bid  = blockIdx.x + 16 * blockIdx.y;
    const int xcd  = bid & 7, slot = bid >> 3;
    const int bh   = 4 * xcd + (slot >> 4);
    const int q0   = (slot & 15) * 128;
    const int q    = q0 + w4 * 32 + l31;             // partner waves share q

    // Q B-fragments: qf[j] = Q[q][16j + 8h .. +8]
    const size_t qbase = ((size_t)bh * SEQ + q) * DK;
    bf16x8 qf[4];
    #pragma unroll
    for (int j = 0; j < 4; ++j)
        qf[j] = *reinterpret_cast<const bf16x8*>(&q_ws[qbase + j * 16 + h * 8]);

    const short one_bf = (short)0x3F80;
    const bf16x8 onesf = {one_bf, one_bf, one_bf, one_bf, one_bf, one_bf, one_bf, one_bf};

    // staging: wave stages rows [w4*16, w4*16+16) of its stream's tile
    const int l8 = lane >> 3, l7 = lane & 7;
    const int scol = 8 * (l7 ^ l8);          // pre-swizzled global column
    const unsigned short* kp0 = &k_ws [((size_t)bh * SEQ + s * 1024 + w4 * 16 + l8) * DK + scol];
    const unsigned short* kp1 = kp0 + 8 * DK;
    const unsigned short* vp0 = &vt_ws[((size_t)bh * DK + w4 * 16 + l8) * SEQ + s * 1024 + scol];
    const unsigned short* vp1 = vp0 + 8 * SEQ;

    // fragment-read swizzle: row&7 = l31&7
    const int r7 = l31 & 7;
    const unsigned short* pK[4];
    const unsigned short* pV[4];
    #pragma unroll
    for (int j = 0; j < 4; ++j) {
        const int ck = 8 * (((j << 1) + h) ^ r7);   // logical col16 = 16j+8h
        pK[j] = &lds4[2 * s][l31 * 64 + ck];
        pV[j] = &lds4[4 + 2 * s][l31 * 64 + ck];
    }

    f32x16 oacc[2] = {};
    f32x16 lacc = {};

    const int dst0 = w4 * 2 * 512, dst1 = (w4 * 2 + 1) * 512;

    auto stage = [&](int b) {                // b: 0 or 1 within stream
        __builtin_amdgcn_global_load_lds(
            (const __attribute__((address_space(1))) unsigned int*)kp0,
            (__attribute__((address_space(3))) unsigned int*)&lds4[2 * s + b][dst0], 16, 0, 0);
        __builtin_amdgcn_global_load_lds(
            (const __attribute__((address_space(1))) unsigned int*)kp1,
            (__attribute__((address_space(3))) unsigned int*)&lds4[2 * s + b][dst1], 16, 0, 0);
        __builtin_amdgcn_global_load_lds(
            (const __attribute__((address_space(1))) unsigned int*)vp0,
            (__attribute__((address_space(3))) unsigned int*)&lds4[4 + 2 * s + b][dst0], 16, 0, 0);
        __builtin_amdgcn_global_load_lds(
            (const __attribute__((address_space(1))) unsigned int*)vp1,
            (__attribute__((address_space(3))) unsigned int*)&lds4[4 + 2 * s + b][dst1], 16, 0, 0);
        kp0 += 64 * DK; kp1 += 64 * DK;
        vp0 += 64;      vp1 += 64;
    };

    auto compute = [&](int OFF) {            // OFF = 0 or 4096 (buffer in stream)
        // ---- S^T = mfma32(K, Q): two 32-key subtiles
        f32x16 st0 = {}, st1 = {};
        __builtin_amdgcn_s_setprio(1);
        #pragma unroll
        for (int j = 0; j < 4; ++j) {
            const bf16x8 k0 = *reinterpret_cast<const bf16x8*>(pK[j] + OFF);
            const bf16x8 k1 = *reinterpret_cast<const bf16x8*>(pK[j] + OFF + 2048);
            st0 = __builtin_amdgcn_mfma_f32_32x32x16_bf16(k0, qf[j], st0, 0, 0, 0);
            st1 = __builtin_amdgcn_mfma_f32_32x32x16_bf16(k1, qf[j], st1, 0, 0, 0);
        }
        __builtin_amdgcn_s_setprio(0);

        // ---- p = exp2(st) -> PV B-fragments (cvt_pk + permlane32_swap)
        bf16x8 pb[4];
        #pragma unroll
        for (int ss = 0; ss < 2; ++ss) {
            #pragma unroll
            for (int jg = 0; jg < 2; ++jg) {
                const int rb = 8 * jg;
                float e0, e1, e2, e3, e4, e5, e6, e7;
                #define EXP2(dst, src) asm("v_exp_f32 %0, %1" : "=v"(dst) : "v"(src))
                if (ss == 0) {
                    EXP2(e0, st0[rb + 0]); EXP2(e1, st0[rb + 1]);
                    EXP2(e2, st0[rb + 2]); EXP2(e3, st0[rb + 3]);
                    EXP2(e4, st0[rb + 4]); EXP2(e5, st0[rb + 5]);
                    EXP2(e6, st0[rb + 6]); EXP2(e7, st0[rb + 7]);
                } else {
                    EXP2(e0, st1[rb + 0]); EXP2(e1, st1[rb + 1]);
                    EXP2(e2, st1[rb + 2]); EXP2(e3, st1[rb + 3]);
                    EXP2(e4, st1[rb + 4]); EXP2(e5, st1[rb + 5]);
                    EXP2(e6, st1[rb + 6]); EXP2(e7, st1[rb + 7]);
                }
                #undef EXP2
                unsigned int wA, wB, wC, wD;
                asm("v_cvt_pk_bf16_f32 %0, %1, %2" : "=v"(wA) : "v"(e0), "v"(e1));
                asm("v_cvt_pk_bf16_f32 %0, %1, %2" : "=v"(wB) : "v"(e2), "v"(e3));
                asm("v_cvt_pk_bf16_f32 %0, %1, %2" : "=v"(wC) : "v"(e4), "v"(e5));
                asm("v_cvt_pk_bf16_f32 %0, %1, %2" : "=v"(wD) : "v"(e6), "v"(e7));
                asm("v_permlane32_swap_b32 %0, %1" : "+v"(wA), "+v"(wC));
                asm("v_permlane32_swap_b32 %0, %1" : "+v"(wB), "+v"(wD));
                uint4 ww;
                ww.x = wA; ww.y = wB; ww.z = wC; ww.w = wD;
                pb[2 * ss + jg] = __builtin_bit_cast(bf16x8, ww);
            }
        }

        // ---- l on MFMA pipe; O^T += mfma32(V^T, P)
        __builtin_amdgcn_s_setprio(1);
        #pragma unroll
        for (int jg = 0; jg < 4; ++jg)
            lacc = __builtin_amdgcn_mfma_f32_32x32x16_bf16(onesf, pb[jg], lacc, 0, 0, 0);
        #pragma unroll
        for (int dt = 0; dt < 2; ++dt)
            #pragma unroll
            for (int jg = 0; jg < 4; ++jg) {
                const bf16x8 vv = *reinterpret_cast<const bf16x8*>(pV[jg] + OFF + dt * 2048);
                oacc[dt] = __builtin_amdgcn_mfma_f32_32x32x16_bf16(vv, pb[jg], oacc[dt], 0, 0, 0);
            }
        __builtin_amdgcn_s_setprio(0);
    };

    // ---- prologue + main: 16 tiles per stream, 2-buffer schedule
    stage(0);
    __syncthreads();
    #pragma unroll 1
    for (int tt = 0; tt < 8; ++tt) {
        stage(1);
        compute(0);
        __syncthreads();
        if (tt < 7) stage(0);
        compute(4096);
        __syncthreads();
    }

    // ---- in-block split-K combine through LDS (stride 33 -> 2-way banks)
    float* fl = (float*)&lds4[0][0];
    if (s == 1) {
        float* p = fl + (size_t)(w4 * 64 + lane) * 33;
        #pragma unroll
        for (int dt = 0; dt < 2; ++dt)
            #pragma unroll
            for (int r = 0; r < 16; ++r) p[dt * 16 + r] = oacc[dt][r];
        p[32] = lacc[0];
    }
    __syncthreads();
    if (s == 0) {
        const float* p = fl + (size_t)(w4 * 64 + lane) * 33;
        #pragma unroll
        for (int dt = 0; dt < 2; ++dt)
            #pragma unroll
            for (int r = 0; r < 16; ++r) oacc[dt][r] += p[dt * 16 + r];
        const float rl = 1.0f / (lacc[0] + p[32]);

        // epilogue: reg r -> d = dt*32 + (r&3) + 8*(r>>2) + 4h
        const int b_ = bh >> 4, hh = bh & 15;
        unsigned short* aop = &ao_ws[(size_t)(b_ * SEQ + q) * DM + hh * 64];
        #pragma unroll
        for (int dt = 0; dt < 2; ++dt) {
            #pragma unroll
            for (int qd = 0; qd < 4; ++qd) {
                ushort4 o;
                o.x = f2bf(oacc[dt][4 * qd + 0] * rl);
                o.y = f2bf(oacc[dt][4 * qd + 1] * rl);
                o.z = f2bf(oacc[dt][4 * qd + 2] * rl);
                o.w = f2bf(oacc[dt][4 * qd + 3] * rl);
                *reinterpret_cast<ushort4*>(&aop[dt * 32 + 8 * qd + 4 * h]) = o;
            }
        }
    }
}

// ---------------------------------------------------------------------------
// LayerNorm + LeakyReLU, one block per row; h bf16 (r22 traffic trim)
// ---------------------------------------------------------------------------
__global__ __launch_bounds__(256)
void ln_kernel(const unsigned short* __restrict__ hb, const float* __restrict__ gamma,
               const float* __restrict__ beta, float* __restrict__ out)
{
    __shared__ float s1[4], s2[4];
    const int row = blockIdx.x, tid = threadIdx.x;
    const ushort4 hv = reinterpret_cast<const ushort4*>(hb + (size_t)row * DM)[tid];
    float4 v;
    v.x = bf2f(hv.x); v.y = bf2f(hv.y); v.z = bf2f(hv.z); v.w = bf2f(hv.w);
    float sum = v.x + v.y + v.z + v.w;
    float sq  = v.x * v.x + v.y * v.y + v.z * v.z + v.w * v.w;
    #pragma unroll
    for (int mk = 1; mk <= 32; mk <<= 1) {
        sum += __shfl_xor(sum, mk);
        sq  += __shfl_xor(sq, mk);
    }
    if ((tid & 63) == 0) { s1[tid >> 6] = sum; s2[tid >> 6] = sq; }
    __syncthreads();
    sum = s1[0] + s1[1] + s1[2] + s1[3];
    sq  = s2[0] + s2[1] + s2[2] + s2[3];
    const float mu = sum * (1.f / DM);
    const float var = sq * (1.f / DM) - mu * mu;
    const float rstd = rsqrtf(var + 1e-5f);
    const float4 gv = reinterpret_cast<const float4*>(gamma)[tid];
    const float4 bv = reinterpret_cast<const float4*>(beta)[tid];
    float4 o;
    o.x = (v.x - mu) * rstd * gv.x + bv.x;
    o.y = (v.y - mu) * rstd * gv.y + bv.y;
    o.z = (v.z - mu) * rstd * gv.z + bv.z;
    o.w = (v.w - mu) * rstd * gv.w + bv.w;
    o.x = o.x >= 0.f ? o.x : 0.01f * o.x;
    o.y = o.y >= 0.f ? o.y : 0.01f * o.y;
    o.z = o.z >= 0.f ? o.z : 0.01f * o.z;
    o.w = o.w >= 0.f ? o.w : 0.01f * o.w;
    reinterpret_cast<float4*>(out + (size_t)row * DM)[tid] = o;
}

extern "C" void kernel_launch(void* const* d_in, const int* in_sizes, int n_in,
                              void* d_out, int out_size, void* d_ws, size_t ws_size,
                              hipStream_t stream)
{
    const float* x     = (const float*)d_in[0];
    const float* Wq    = (const float*)d_in[1];
    const float* bq    = (const float*)d_in[2];
    const float* Wk    = (const float*)d_in[3];
    const float* bk    = (const float*)d_in[4];
    const float* Wv    = (const float*)d_in[5];
    const float* bv    = (const float*)d_in[6];
    const float* Wo    = (const float*)d_in[7];
    const float* bo    = (const float*)d_in[8];
    const float* gamma = (const float*)d_in[9];
    const float* beta  = (const float*)d_in[10];

    // workspace layout (48 MB):
    // [0,8M) q | [8,16M) k | [16,24M) vt | [24,32M) ao
    // [32,40M) xb | [40,46M) wqkvb | [46,48M) wob
    // h (bf16, 8MB) reuses [0,8M) after attn (q dead)
    char* ws = (char*)d_ws;
    unsigned short* q_ws   = (unsigned short*)(ws);
    unsigned short* k_ws   = (unsigned short*)(ws + (8u << 20));
    unsigned short* vt_ws  = (unsigned short*)(ws + (16u << 20));
    unsigned short* ao_ws  = (unsigned short*)(ws + (24u << 20));
    unsigned short* xb_ws  = (unsigned short*)(ws + (32u << 20));
    unsigned short* wqkv_b = (unsigned short*)(ws + (40u << 20));
    unsigned short* wo_b   = (unsigned short*)(ws + (46u << 20));
    unsigned short* hb_ws  = (unsigned short*)(ws);

    const dim3 blk(256);
    cvt_kernel<<<dim3(1024, 5), blk, 0, stream>>>(
        x, Wq, Wk, Wv, Wo, xb_ws, wqkv_b, wo_b);
    gemm2_kernel<0, 64, 128><<<dim3(8, 64, 3), blk, 0, stream>>>(
        xb_ws, wqkv_b, bq, bk, bv, q_ws, k_ws, vt_ws, nullptr, nullptr);
    attn_kernel<<<dim3(16, 32), dim3(512), 0, stream>>>(q_ws, k_ws, vt_ws, ao_ws);
    gemm2_kernel<1, 64, 64><<<dim3(16, 64, 1), blk, 0, stream>>>(
        ao_ws, wo_b, bo, nullptr, nullptr, nullptr, nullptr, nullptr, x, hb_ws);
    ln_kernel<<<dim3(4096), blk, 0, stream>>>(hb_ws, gamma, beta, (float*)d_out);
}

// Round 24
// 122.130 us; speedup vs baseline: 1.1457x; 1.1457x over previous
//
#include <hip/hip_runtime.h>

#define DM   1024
#define NH   16
#define DK   64
#define SEQ  2048
#define BATCH 2

typedef __attribute__((ext_vector_type(8))) short bf16x8;
typedef __attribute__((ext_vector_type(4))) float f32x4;
typedef __attribute__((ext_vector_type(16))) float f32x16;

__device__ __forceinline__ unsigned short f2bf(float f) {
    unsigned int u = __builtin_bit_cast(unsigned int, f);
    u += 0x7FFFu + ((u >> 16) & 1u);
    return (unsigned short)(u >> 16);
}
__device__ __forceinline__ float bf2f(unsigned short u) {
    return __builtin_bit_cast(float, ((unsigned int)u) << 16);
}

// ---------------------------------------------------------------------------
// fp32 -> bf16 pre-convert: x (4M elems), Wq/Wk/Wv (-> wqkvb contig), Wo.
// ---------------------------------------------------------------------------
__global__ __launch_bounds__(256)
void cvt_kernel(const float* __restrict__ x,
                const float* __restrict__ wq, const float* __restrict__ wk,
                const float* __restrict__ wv, const float* __restrict__ wo,
                unsigned short* __restrict__ xb,
                unsigned short* __restrict__ wqkvb,
                unsigned short* __restrict__ wob)
{
    const int seg = blockIdx.y;
    const float* src;
    unsigned short* dst;
    int n;
    if (seg == 0)      { src = x;  dst = xb;                  n = 4 << 20; }
    else if (seg == 1) { src = wq; dst = wqkvb;               n = 1 << 20; }
    else if (seg == 2) { src = wk; dst = wqkvb + (1 << 20);   n = 1 << 20; }
    else if (seg == 3) { src = wv; dst = wqkvb + (2 << 20);   n = 1 << 20; }
    else               { src = wo; dst = wob;                 n = 1 << 20; }
    for (int i = (blockIdx.x * 256 + threadIdx.x) * 4; i < n; i += 1024 * 256 * 4) {
        const float4 v = *reinterpret_cast<const float4*>(&src[i]);
        ushort4 o;
        o.x = f2bf(v.x); o.y = f2bf(v.y); o.z = f2bf(v.z); o.w = f2bf(v.w);
        *reinterpret_cast<ushort4*>(&dst[i]) = o;
    }
}

// ---------------------------------------------------------------------------
// bf16 GEMM, m97 structure, BK=32, BM=128 single-buffered, DEFAULT block
// order — measured optimum of this template family (r6/r14/r16/r18/r22;
// neighbors BK=64, BM=64, dbuf, XCD-remap all measured worse).
// global_load_lds width-16 staging, BN template.
// C[m][n] = sum_k A[m][k] * W[n][k] + bias[n]
// MODE 0: z in {0,1,2} -> Q (scaled log2e/8) / K / V^T   (bf16 out)
// MODE 1: + residual (fp32 math) -> h stored BF16
// ---------------------------------------------------------------------------
template <int MODE, int BN>
__global__ __launch_bounds__(256)
void gemm2_kernel(const unsigned short* __restrict__ Ab,
                  const unsigned short* __restrict__ Wall,
                  const float* __restrict__ B0, const float* __restrict__ B1,
                  const float* __restrict__ B2,
                  unsigned short* __restrict__ q_ws,
                  unsigned short* __restrict__ k_ws,
                  unsigned short* __restrict__ vt_ws,
                  const float* __restrict__ resid,
                  unsigned short* __restrict__ hb_ws)
{
    __shared__ unsigned short sA[128 * 32];
    __shared__ unsigned short sB[BN * 32];

    const int tid = threadIdx.x, lane = tid & 63, wid = tid >> 6;
    const int n0 = blockIdx.x * BN, m0 = blockIdx.y * 128;
    const int z  = (MODE == 0) ? blockIdx.z : 0;
    const unsigned short* W = Wall + (size_t)z * (1 << 20);
    const float* bias = (MODE == 0) ? (z == 0 ? B0 : (z == 1 ? B1 : B2)) : B0;

    const int g = lane >> 4, lq = lane & 15;
    const int wr = wid >> 1, wc = wid & 1;
    const int rA = lane >> 2;            // row within 16-row chunk
    const int csh = (lane & 3) * 8;      // col (shorts) within 32-col tile

    f32x4 acc[4][BN / 32] = {};

    for (int k0 = 0; k0 < DM; k0 += 32) {
        #pragma unroll
        for (int i = 0; i < 2; ++i) {
            const int c = wid * 2 + i;   // 1KB chunk = 16 rows
            __builtin_amdgcn_global_load_lds(
                (const __attribute__((address_space(1))) unsigned int*)
                    &Ab[(size_t)(m0 + c * 16 + rA) * DM + k0 + csh],
                (__attribute__((address_space(3))) unsigned int*)&sA[c * 512],
                16, 0, 0);
        }
        #pragma unroll
        for (int i = 0; i < BN / 64; ++i) {
            const int c = wid * (BN / 64) + i;
            __builtin_amdgcn_global_load_lds(
                (const __attribute__((address_space(1))) unsigned int*)
                    &W[(size_t)(n0 + c * 16 + rA) * DM + k0 + csh],
                (__attribute__((address_space(3))) unsigned int*)&sB[c * 512],
                16, 0, 0);
        }
        __syncthreads();   // implicit vmcnt(0) drains the DMA

        bf16x8 a[4], b[BN / 32];
        #pragma unroll
        for (int m = 0; m < 4; ++m)
            a[m] = *reinterpret_cast<const bf16x8*>(&sA[(wr * 64 + m * 16 + lq) * 32 + 8 * g]);
        #pragma unroll
        for (int n = 0; n < BN / 32; ++n)
            b[n] = *reinterpret_cast<const bf16x8*>(&sB[(wc * (BN / 2) + n * 16 + lq) * 32 + 8 * g]);
        #pragma unroll
        for (int m = 0; m < 4; ++m)
            #pragma unroll
            for (int n = 0; n < BN / 32; ++n)
                acc[m][n] = __builtin_amdgcn_mfma_f32_16x16x32_bf16(
                    a[m], b[n], acc[m][n], 0, 0, 0);
        __syncthreads();
    }

    // epilogue: D row = 4*g + j (A-side), col = lq (B-side)
    #pragma unroll
    for (int m = 0; m < 4; ++m) {
        #pragma unroll
        for (int n = 0; n < BN / 32; ++n) {
            #pragma unroll
            for (int j = 0; j < 4; ++j) {
                const int row = m0 + wr * 64 + m * 16 + 4 * g + j;
                const int col = n0 + wc * (BN / 2) + n * 16 + lq;
                float v = acc[m][n][j] + bias[col];
                if constexpr (MODE == 0) {
                    const int b_ = row >> 11, s = row & (SEQ - 1);
                    const int hh = col >> 6,  d = col & (DK - 1);
                    if (z == 0)   // fold 1/sqrt(64) * log2(e): attn in exp2 domain
                        q_ws[(((size_t)(b_ * NH + hh) * SEQ + s) << 6) + d] = f2bf(v * 0.18033688f);
                    else if (z == 1)
                        k_ws[(((size_t)(b_ * NH + hh) * SEQ + s) << 6) + d] = f2bf(v);
                    else
                        vt_ws[((size_t)(b_ * NH + hh) * DK + d) * SEQ + s] = f2bf(v);
                } else {
                    const size_t idx = (size_t)row * DM + col;
                    hb_ws[idx] = f2bf(v + resid[idx]);   // residual fp32, store bf16
                }
            }
        }
    }
}

// ---------------------------------------------------------------------------
// Flash attention, 32x32x16 swapped-operand, fixed-max softmax, in-block
// 2-way split-K + XCD remap — EXACT r18 measured-best (48.3us, FETCH 12MB).
// ---------------------------------------------------------------------------
__global__ __launch_bounds__(512)
void attn_kernel(const unsigned short* __restrict__ q_ws,
                 const unsigned short* __restrict__ k_ws,
                 const unsigned short* __restrict__ vt_ws,
                 unsigned short* __restrict__ ao_ws)
{
    // stream s: K bufs lds4[2s],[2s+1]; V bufs lds4[4+2s],[4+2s+1]
    __shared__ unsigned short lds4[8][4096];

    const int tid = threadIdx.x;
    const int lane = tid & 63, wid = tid >> 6;       // wid 0..7
    const int s = wid >> 2, w4 = wid & 3;
    const int l31 = lane & 31, h = lane >> 5;

    // XCD-aware remap (bijection over 512 blocks)
    const int bid  = blockIdx.x + 16 * blockIdx.y;
    const int xcd  = bid & 7, slot = bid >> 3;
    const int bh   = 4 * xcd + (slot >> 4);
    const int q0   = (slot & 15) * 128;
    const int q    = q0 + w4 * 32 + l31;             // partner waves share q

    // Q B-fragments: qf[j] = Q[q][16j + 8h .. +8]
    const size_t qbase = ((size_t)bh * SEQ + q) * DK;
    bf16x8 qf[4];
    #pragma unroll
    for (int j = 0; j < 4; ++j)
        qf[j] = *reinterpret_cast<const bf16x8*>(&q_ws[qbase + j * 16 + h * 8]);

    const short one_bf = (short)0x3F80;
    const bf16x8 onesf = {one_bf, one_bf, one_bf, one_bf, one_bf, one_bf, one_bf, one_bf};

    // staging: wave stages rows [w4*16, w4*16+16) of its stream's tile
    const int l8 = lane >> 3, l7 = lane & 7;
    const int scol = 8 * (l7 ^ l8);          // pre-swizzled global column
    const unsigned short* kp0 = &k_ws [((size_t)bh * SEQ + s * 1024 + w4 * 16 + l8) * DK + scol];
    const unsigned short* kp1 = kp0 + 8 * DK;
    const unsigned short* vp0 = &vt_ws[((size_t)bh * DK + w4 * 16 + l8) * SEQ + s * 1024 + scol];
    const unsigned short* vp1 = vp0 + 8 * SEQ;

    // fragment-read swizzle: row&7 = l31&7
    const int r7 = l31 & 7;
    const unsigned short* pK[4];
    const unsigned short* pV[4];
    #pragma unroll
    for (int j = 0; j < 4; ++j) {
        const int ck = 8 * (((j << 1) + h) ^ r7);   // logical col16 = 16j+8h
        pK[j] = &lds4[2 * s][l31 * 64 + ck];
        pV[j] = &lds4[4 + 2 * s][l31 * 64 + ck];
    }

    f32x16 oacc[2] = {};
    f32x16 lacc = {};

    const int dst0 = w4 * 2 * 512, dst1 = (w4 * 2 + 1) * 512;

    auto stage = [&](int b) {                // b: 0 or 1 within stream
        __builtin_amdgcn_global_load_lds(
            (const __attribute__((address_space(1))) unsigned int*)kp0,
            (__attribute__((address_space(3))) unsigned int*)&lds4[2 * s + b][dst0], 16, 0, 0);
        __builtin_amdgcn_global_load_lds(
            (const __attribute__((address_space(1))) unsigned int*)kp1,
            (__attribute__((address_space(3))) unsigned int*)&lds4[2 * s + b][dst1], 16, 0, 0);
        __builtin_amdgcn_global_load_lds(
            (const __attribute__((address_space(1))) unsigned int*)vp0,
            (__attribute__((address_space(3))) unsigned int*)&lds4[4 + 2 * s + b][dst0], 16, 0, 0);
        __builtin_amdgcn_global_load_lds(
            (const __attribute__((address_space(1))) unsigned int*)vp1,
            (__attribute__((address_space(3))) unsigned int*)&lds4[4 + 2 * s + b][dst1], 16, 0, 0);
        kp0 += 64 * DK; kp1 += 64 * DK;
        vp0 += 64;      vp1 += 64;
    };

    auto compute = [&](int OFF) {            // OFF = 0 or 4096 (buffer in stream)
        // ---- S^T = mfma32(K, Q): two 32-key subtiles
        f32x16 st0 = {}, st1 = {};
        __builtin_amdgcn_s_setprio(1);
        #pragma unroll
        for (int j = 0; j < 4; ++j) {
            const bf16x8 k0 = *reinterpret_cast<const bf16x8*>(pK[j] + OFF);
            const bf16x8 k1 = *reinterpret_cast<const bf16x8*>(pK[j] + OFF + 2048);
            st0 = __builtin_amdgcn_mfma_f32_32x32x16_bf16(k0, qf[j], st0, 0, 0, 0);
            st1 = __builtin_amdgcn_mfma_f32_32x32x16_bf16(k1, qf[j], st1, 0, 0, 0);
        }
        __builtin_amdgcn_s_setprio(0);

        // ---- p = exp2(st) -> PV B-fragments (cvt_pk + permlane32_swap)
        bf16x8 pb[4];
        #pragma unroll
        for (int ss = 0; ss < 2; ++ss) {
            #pragma unroll
            for (int jg = 0; jg < 2; ++jg) {
                const int rb = 8 * jg;
                float e0, e1, e2, e3, e4, e5, e6, e7;
                #define EXP2(dst, src) asm("v_exp_f32 %0, %1" : "=v"(dst) : "v"(src))
                if (ss == 0) {
                    EXP2(e0, st0[rb + 0]); EXP2(e1, st0[rb + 1]);
                    EXP2(e2, st0[rb + 2]); EXP2(e3, st0[rb + 3]);
                    EXP2(e4, st0[rb + 4]); EXP2(e5, st0[rb + 5]);
                    EXP2(e6, st0[rb + 6]); EXP2(e7, st0[rb + 7]);
                } else {
                    EXP2(e0, st1[rb + 0]); EXP2(e1, st1[rb + 1]);
                    EXP2(e2, st1[rb + 2]); EXP2(e3, st1[rb + 3]);
                    EXP2(e4, st1[rb + 4]); EXP2(e5, st1[rb + 5]);
                    EXP2(e6, st1[rb + 6]); EXP2(e7, st1[rb + 7]);
                }
                #undef EXP2
                unsigned int wA, wB, wC, wD;
                asm("v_cvt_pk_bf16_f32 %0, %1, %2" : "=v"(wA) : "v"(e0), "v"(e1));
                asm("v_cvt_pk_bf16_f32 %0, %1, %2" : "=v"(wB) : "v"(e2), "v"(e3));
                asm("v_cvt_pk_bf16_f32 %0, %1, %2" : "=v"(wC) : "v"(e4), "v"(e5));
                asm("v_cvt_pk_bf16_f32 %0, %1, %2" : "=v"(wD) : "v"(e6), "v"(e7));
                asm("v_permlane32_swap_b32 %0, %1" : "+v"(wA), "+v"(wC));
                asm("v_permlane32_swap_b32 %0, %1" : "+v"(wB), "+v"(wD));
                uint4 ww;
                ww.x = wA; ww.y = wB; ww.z = wC; ww.w = wD;
                pb[2 * ss + jg] = __builtin_bit_cast(bf16x8, ww);
            }
        }

        // ---- l on MFMA pipe; O^T += mfma32(V^T, P)
        __builtin_amdgcn_s_setprio(1);
        #pragma unroll
        for (int jg = 0; jg < 4; ++jg)
            lacc = __builtin_amdgcn_mfma_f32_32x32x16_bf16(onesf, pb[jg], lacc, 0, 0, 0);
        #pragma unroll
        for (int dt = 0; dt < 2; ++dt)
            #pragma unroll
            for (int jg = 0; jg < 4; ++jg) {
                const bf16x8 vv = *reinterpret_cast<const bf16x8*>(pV[jg] + OFF + dt * 2048);
                oacc[dt] = __builtin_amdgcn_mfma_f32_32x32x16_bf16(vv, pb[jg], oacc[dt], 0, 0, 0);
            }
        __builtin_amdgcn_s_setprio(0);
    };

    // ---- prologue + main: 16 tiles per stream, 2-buffer schedule
    stage(0);
    __syncthreads();
    #pragma unroll 1
    for (int tt = 0; tt < 8; ++tt) {
        stage(1);
        compute(0);
        __syncthreads();
        if (tt < 7) stage(0);
        compute(4096);
        __syncthreads();
    }

    // ---- in-block split-K combine through LDS (stride 33 -> 2-way banks)
    float* fl = (float*)&lds4[0][0];
    if (s == 1) {
        float* p = fl + (size_t)(w4 * 64 + lane) * 33;
        #pragma unroll
        for (int dt = 0; dt < 2; ++dt)
            #pragma unroll
            for (int r = 0; r < 16; ++r) p[dt * 16 + r] = oacc[dt][r];
        p[32] = lacc[0];
    }
    __syncthreads();
    if (s == 0) {
        const float* p = fl + (size_t)(w4 * 64 + lane) * 33;
        #pragma unroll
        for (int dt = 0; dt < 2; ++dt)
            #pragma unroll
            for (int r = 0; r < 16; ++r) oacc[dt][r] += p[dt * 16 + r];
        const float rl = 1.0f / (lacc[0] + p[32]);

        // epilogue: reg r -> d = dt*32 + (r&3) + 8*(r>>2) + 4h
        const int b_ = bh >> 4, hh = bh & 15;
        unsigned short* aop = &ao_ws[(size_t)(b_ * SEQ + q) * DM + hh * 64];
        #pragma unroll
        for (int dt = 0; dt < 2; ++dt) {
            #pragma unroll
            for (int qd = 0; qd < 4; ++qd) {
                ushort4 o;
                o.x = f2bf(oacc[dt][4 * qd + 0] * rl);
                o.y = f2bf(oacc[dt][4 * qd + 1] * rl);
                o.z = f2bf(oacc[dt][4 * qd + 2] * rl);
                o.w = f2bf(oacc[dt][4 * qd + 3] * rl);
                *reinterpret_cast<ushort4*>(&aop[dt * 32 + 8 * qd + 4 * h]) = o;
            }
        }
    }
}

// ---------------------------------------------------------------------------
// LayerNorm + LeakyReLU, one block per row; h bf16 (r22 traffic trim)
// ---------------------------------------------------------------------------
__global__ __launch_bounds__(256)
void ln_kernel(const unsigned short* __restrict__ hb, const float* __restrict__ gamma,
               const float* __restrict__ beta, float* __restrict__ out)
{
    __shared__ float s1[4], s2[4];
    const int row = blockIdx.x, tid = threadIdx.x;
    const ushort4 hv = reinterpret_cast<const ushort4*>(hb + (size_t)row * DM)[tid];
    float4 v;
    v.x = bf2f(hv.x); v.y = bf2f(hv.y); v.z = bf2f(hv.z); v.w = bf2f(hv.w);
    float sum = v.x + v.y + v.z + v.w;
    float sq  = v.x * v.x + v.y * v.y + v.z * v.z + v.w * v.w;
    #pragma unroll
    for (int mk = 1; mk <= 32; mk <<= 1) {
        sum += __shfl_xor(sum, mk);
        sq  += __shfl_xor(sq, mk);
    }
    if ((tid & 63) == 0) { s1[tid >> 6] = sum; s2[tid >> 6] = sq; }
    __syncthreads();
    sum = s1[0] + s1[1] + s1[2] + s1[3];
    sq  = s2[0] + s2[1] + s2[2] + s2[3];
    const float mu = sum * (1.f / DM);
    const float var = sq * (1.f / DM) - mu * mu;
    const float rstd = rsqrtf(var + 1e-5f);
    const float4 gv = reinterpret_cast<const float4*>(gamma)[tid];
    const float4 bv = reinterpret_cast<const float4*>(beta)[tid];
    float4 o;
    o.x = (v.x - mu) * rstd * gv.x + bv.x;
    o.y = (v.y - mu) * rstd * gv.y + bv.y;
    o.z = (v.z - mu) * rstd * gv.z + bv.z;
    o.w = (v.w - mu) * rstd * gv.w + bv.w;
    o.x = o.x >= 0.f ? o.x : 0.01f * o.x;
    o.y = o.y >= 0.f ? o.y : 0.01f * o.y;
    o.z = o.z >= 0.f ? o.z : 0.01f * o.z;
    o.w = o.w >= 0.f ? o.w : 0.01f * o.w;
    reinterpret_cast<float4*>(out + (size_t)row * DM)[tid] = o;
}

extern "C" void kernel_launch(void* const* d_in, const int* in_sizes, int n_in,
                              void* d_out, int out_size, void* d_ws, size_t ws_size,
                              hipStream_t stream)
{
    const float* x     = (const float*)d_in[0];
    const float* Wq    = (const float*)d_in[1];
    const float* bq    = (const float*)d_in[2];
    const float* Wk    = (const float*)d_in[3];
    const float* bk    = (const float*)d_in[4];
    const float* Wv    = (const float*)d_in[5];
    const float* bv    = (const float*)d_in[6];
    const float* Wo    = (const float*)d_in[7];
    const float* bo    = (const float*)d_in[8];
    const float* gamma = (const float*)d_in[9];
    const float* beta  = (const float*)d_in[10];

    // workspace layout (48 MB):
    // [0,8M) q | [8,16M) k | [16,24M) vt | [24,32M) ao
    // [32,40M) xb | [40,46M) wqkvb | [46,48M) wob
    // h (bf16, 8MB) reuses [0,8M) after attn (q dead)
    char* ws = (char*)d_ws;
    unsigned short* q_ws   = (unsigned short*)(ws);
    unsigned short* k_ws   = (unsigned short*)(ws + (8u << 20));
    unsigned short* vt_ws  = (unsigned short*)(ws + (16u << 20));
    unsigned short* ao_ws  = (unsigned short*)(ws + (24u << 20));
    unsigned short* xb_ws  = (unsigned short*)(ws + (32u << 20));
    unsigned short* wqkv_b = (unsigned short*)(ws + (40u << 20));
    unsigned short* wo_b   = (unsigned short*)(ws + (46u << 20));
    unsigned short* hb_ws  = (unsigned short*)(ws);

    const dim3 blk(256);
    cvt_kernel<<<dim3(1024, 5), blk, 0, stream>>>(
        x, Wq, Wk, Wv, Wo, xb_ws, wqkv_b, wo_b);
    gemm2_kernel<0, 128><<<dim3(8, 32, 3), blk, 0, stream>>>(
        xb_ws, wqkv_b, bq, bk, bv, q_ws, k_ws, vt_ws, nullptr, nullptr);
    attn_kernel<<<dim3(16, 32), dim3(512), 0, stream>>>(q_ws, k_ws, vt_ws, ao_ws);
    gemm2_kernel<1, 64><<<dim3(16, 32, 1), blk, 0, stream>>>(
        ao_ws, wo_b, bo, nullptr, nullptr, nullptr, nullptr, nullptr, x, hb_ws);
    ln_kernel<<<dim3(4096), blk, 0, stream>>>(hb_ws, gamma, beta, (float*)d_out);
}